// Round 22
// baseline (225.156 us; speedup 1.0000x reference)
//
#include <hip/hip_runtime.h>
#include <hip/hip_bf16.h>
#include <hip/hip_fp16.h>

// DeepSetPred R22 = R21 (212.4us) with the last unexplored config cell:
// 128-token tile + 16 waves (1024 thr, 1 block/CU, 4 waves/SIMD = R21's TLP)
// + R21's MT=2/NT=2 per-wave geometry via (8 f-waves x 2 t-halves).
// Halves A/L2 weight traffic to 1GB (t-twins share A-frags via L1/L2);
// keeps B-reuse-8 (8 f-waves per 64-token half). R17 tested this tile with
// the WRONG geometry (MT=1/NT=4, B-reuse halved) - that was its failure.

typedef _Float16 half8v __attribute__((ext_vector_type(8)));
typedef _Float16 half4v __attribute__((ext_vector_type(4)));
typedef __fp16 fp16x2 __attribute__((ext_vector_type(2)));
typedef float f32x4 __attribute__((ext_vector_type(4)));
typedef float f32x16 __attribute__((ext_vector_type(16)));

#define TANH_SCALE 2.8853900817779268f  // 2*log2(e)
#define E_STRF 129                      // encT row stride (floats)

__device__ __forceinline__ unsigned pkrtz(float a, float b) {
    fp16x2 p = __builtin_amdgcn_cvt_pkrtz(a, b);
    return __builtin_bit_cast(unsigned, p);
}

// ---------------- weight fragmentizer (unchanged) ----------------
// Frag = [32 f][16 k] in MFMA A order: lane l holds f=ft*32+(l&31),
// k=ks*16+(l>>5)*8+j. Layer layout: frag index = ks*NFT + ft, 1KB each.
__global__ __launch_bounds__(256) void wt_kernel(
    const float* __restrict__ W1, const float* __restrict__ W2,
    const float* __restrict__ W3,
    _Float16* __restrict__ F1, _Float16* __restrict__ F2,
    _Float16* __restrict__ F3) {
    int u = blockIdx.x * 256 + threadIdx.x;       // 65536 lane-units
    const float* W; _Float16* F; int FW, NFT, u0; float scale;
    if (u < 16384)      { W = W1; F = F1; FW = 512; NFT = 16; u0 = u;         scale = TANH_SCALE; }
    else if (u < 49152) { W = W2; F = F2; FW = 512; NFT = 16; u0 = u - 16384; scale = TANH_SCALE; }
    else                { W = W3; F = F3; FW = 256; NFT = 8;  u0 = u - 49152; scale = 1.0f; }
    int lane = u0 & 63, frag = u0 >> 6;
    int ft = frag % NFT, ks = frag / NFT;
    int f = ft * 32 + (lane & 31);
    int k0 = ks * 16 + (lane >> 5) * 8;
    half8v v;
    #pragma unroll
    for (int j = 0; j < 8; ++j)
        v[j] = (_Float16)(W[(size_t)(k0 + j) * FW + f] * scale);
    *(half8v*)((char*)F + (size_t)u0 * 16) = v;
}

// ---------------- encoder pass: D[MT*32 f][64 t] at token offset ------------
// A: global frag-ordered, depth-2 ring. B: LDS b128 swizzled rows, depth-1.
// Act row t: 1024B, 16B chunk c stored at (c<<4)^((t&15)<<4).
template<int K, int MT, int NFT>
__device__ __forceinline__ void mlp_pass32(const char* __restrict__ F, int fw,
                                           int tokofs, const char* lds_act,
                                           const float* sbias_layer, int lane,
                                           f32x16 acc[MT][2]) {
    const int r2 = lane & 31;
    const int hi = lane >> 5;
    const int fbase = fw * (MT * 32);
    #pragma unroll
    for (int mt = 0; mt < MT; ++mt)
        #pragma unroll
        for (int q = 0; q < 4; ++q) {
            f32x4 bv = *(const f32x4*)(sbias_layer + fbase + mt * 32 + hi * 4 + q * 8);
            #pragma unroll
            for (int j = 0; j < 4; ++j) {
                acc[mt][0][q * 4 + j] = bv[j];
                acc[mt][1][q * 4 + j] = bv[j];
            }
        }
    const char* fb = F + ((size_t)fw * MT) * 1024 + lane * 16;
    const int xm = (r2 & 15) << 4;
    const char* bb = lds_act + (size_t)(tokofs + r2) * 1024;

    constexpr int NS = K / 16;
    half8v A[3][MT], B[2][2];
    #pragma unroll
    for (int mt = 0; mt < MT; ++mt) {
        A[0][mt] = *(const half8v*)(fb + mt * 1024);
        A[1][mt] = *(const half8v*)(fb + (NFT + mt) * 1024);
    }
    #pragma unroll
    for (int nt = 0; nt < 2; ++nt)
        B[0][nt] = *(const half8v*)(bb + nt * 32768 + ((hi * 16) ^ xm));

    #pragma unroll
    for (int s = 0; s < NS; ++s) {
        if (s + 2 < NS) {
            #pragma unroll
            for (int mt = 0; mt < MT; ++mt)
                A[(s + 2) % 3][mt] =
                    *(const half8v*)(fb + ((size_t)(s + 2) * NFT + mt) * 1024);
        }
        if (s + 1 < NS) {
            int off = ((((s + 1) * 32) | (hi * 16)) ^ xm);
            #pragma unroll
            for (int nt = 0; nt < 2; ++nt)
                B[(s + 1) & 1][nt] = *(const half8v*)(bb + nt * 32768 + off);
        }
        __builtin_amdgcn_s_setprio(1);
        #pragma unroll
        for (int nt = 0; nt < 2; ++nt)
            #pragma unroll
            for (int mt = 0; mt < MT; ++mt)
                acc[mt][nt] = __builtin_amdgcn_mfma_f32_32x32x16_f16(
                    A[s % 3][mt], B[s & 1][nt], acc[mt][nt], 0, 0, 0);
        __builtin_amdgcn_s_setprio(0);
    }
}

// acc -> tanh -> fp16 LDS via cvt_pkrtz, swizzled [t][chunk ^ (t&15)]
template<int MT>
__device__ __forceinline__ void store_h32(char* lds_out, const f32x16 acc[MT][2],
                                          int fbase, int tokofs, int lane) {
    const int t_lo = lane & 31;
    const int hi = lane >> 5;
    #pragma unroll
    for (int mt = 0; mt < MT; ++mt)
        #pragma unroll
        for (int nt = 0; nt < 2; ++nt) {
            int t = tokofs + nt * 32 + t_lo;
            int xm = (t & 15) << 4;
            #pragma unroll
            for (int q = 0; q < 4; ++q) {
                int chunk = (fbase >> 3) + mt * 4 + q;
                float th[4];
                #pragma unroll
                for (int j = 0; j < 4; ++j) {
                    float e = __builtin_amdgcn_exp2f(acc[mt][nt][q * 4 + j]);
                    float rr = __builtin_amdgcn_rcpf(e + 1.0f);
                    th[j] = fmaf(-2.0f, rr, 1.0f);
                }
                uint2 u = { pkrtz(th[0], th[1]), pkrtz(th[2], th[3]) };
                *(uint2*)(lds_out + t * 1024 + ((chunk << 4) ^ xm) + hi * 8) = u;
            }
        }
}

__global__ __launch_bounds__(1024, 4) void encoder_kernel(
    const float* __restrict__ words, const int* __restrict__ seg_ids,
    const _Float16* __restrict__ F1, const _Float16* __restrict__ F2,
    const _Float16* __restrict__ F3,
    const float* __restrict__ b1, const float* __restrict__ b2,
    const float* __restrict__ b3, float* __restrict__ enc) {
    __shared__ __align__(16) char buf[132096];  // act 128x1024 swz / encT 256x129x4
    __shared__ __align__(16) float sbias[1280];
    __shared__ int sseg[128];

    const int tid = threadIdx.x;
    const int lane = tid & 63;
    const int wave = tid >> 6;                  // 0..15
    const int fw = wave >> 1, tw = wave & 1;    // 8 f-waves x 2 t-halves
    const int tok0 = blockIdx.x * 128;

    if (tid < 512) sbias[tid] = b1[tid] * TANH_SCALE;
    else           sbias[tid] = b2[tid - 512] * TANH_SCALE;
    if (tid < 256) sbias[1024 + tid] = b3[tid];
    if (tid < 128) sseg[tid] = seg_ids[tok0 + tid];

    // stage words tile -> fp16 LDS (cvt_pkrtz), swizzled rows
    const float* wsrc = words + (size_t)tok0 * 256;
    #pragma unroll
    for (int it = 0; it < 8; ++it) {
        int i = it * 1024 + tid;           // float4 index, 8192 total
        float4 v = ((const float4*)wsrc)[i];
        int t = i >> 6;
        int col = i & 63;
        uint2 u = { pkrtz(v.x, v.y), pkrtz(v.z, v.w) };
        int off = t * 1024 + (((col >> 1) << 4) ^ ((t & 15) << 4)) + (col & 1) * 8;
        *(uint2*)(buf + off) = u;
    }
    __syncthreads();

    // layer 1: words[128][256] -> h1[128][512] (in place)
    {
        f32x16 acc[2][2];
        mlp_pass32<256, 2, 16>((const char*)F1, fw, tw * 64, buf, sbias, lane, acc);
        __syncthreads();
        store_h32<2>(buf, acc, fw * 64, tw * 64, lane);
    }
    __syncthreads();

    // layer 2: h1 -> h2 (in place)
    {
        f32x16 acc[2][2];
        mlp_pass32<512, 2, 16>((const char*)F2, fw, tw * 64, buf, sbias + 512, lane, acc);
        __syncthreads();
        store_h32<2>(buf, acc, fw * 64, tw * 64, lane);
    }
    __syncthreads();

    // layer 3: h2 -> encT [256][129] f32 (in place; bias folded, no tanh)
    {
        f32x16 acc[1][2];
        mlp_pass32<512, 1, 8>((const char*)F3, fw, tw * 64, buf, sbias + 1024, lane, acc);
        __syncthreads();
        float* encT = (float*)buf;
        const int t_lo = lane & 31;
        const int hi = lane >> 5;
        #pragma unroll
        for (int nt = 0; nt < 2; ++nt) {
            int t = tw * 64 + nt * 32 + t_lo;
            #pragma unroll
            for (int q = 0; q < 4; ++q) {
                int f0 = fw * 32 + hi * 4 + q * 8;
                #pragma unroll
                for (int j = 0; j < 4; ++j)
                    encT[(f0 + j) * E_STRF + t] = acc[0][nt][q * 4 + j];
            }
        }
    }
    __syncthreads();

    // segment reduction: sorted seg_ids -> running sum, atomic on boundary
    {
        int f = tid & 255;
        int qq = tid >> 8;                  // 4 quarters x 32 tokens
        int t0 = qq * 32;
        const float* encT = (const float*)buf;
        float a = 0.0f;
        int cur = sseg[t0];
        for (int i = 0; i < 32; ++i) {
            int t = t0 + i;
            float v = encT[f * E_STRF + t];
            int s = sseg[t];
            if (s != cur) { atomicAdd(&enc[cur * 256 + f], a); a = 0.0f; cur = s; }
            a += v;
        }
        atomicAdd(&enc[cur * 256 + f], a);
    }
}

// ---------------- predictor (tiny, fp32) ----------------
__global__ __launch_bounds__(256) void pred_kernel(
    const float* __restrict__ enc,
    const float* __restrict__ P1, const float* __restrict__ pb1,
    const float* __restrict__ P2, const float* __restrict__ pb2,
    const float* __restrict__ P3, const float* __restrict__ pb3,
    float* __restrict__ out) {
    __shared__ float se[256];
    __shared__ float sp[512];
    __shared__ float red[256];
    const int tid = threadIdx.x, b = blockIdx.x;
    se[tid] = enc[b * 256 + tid];
    __syncthreads();
    float a0 = pb1[tid], a1 = pb1[tid + 256];
    for (int k = 0; k < 256; ++k) {
        float e = se[k];
        a0 = fmaf(e, P1[k * 512 + tid], a0);
        a1 = fmaf(e, P1[k * 512 + tid + 256], a1);
    }
    sp[tid] = tanhf(a0);
    sp[tid + 256] = tanhf(a1);
    __syncthreads();
    a0 = pb2[tid]; a1 = pb2[tid + 256];
    for (int k = 0; k < 512; ++k) {
        float p = sp[k];
        a0 = fmaf(p, P2[k * 512 + tid], a0);
        a1 = fmaf(p, P2[k * 512 + tid + 256], a1);
    }
    __syncthreads();
    sp[tid] = tanhf(a0);
    sp[tid + 256] = tanhf(a1);
    __syncthreads();
    int j = tid & 31, part = tid >> 5;
    float s = 0.0f;
    for (int k = part * 64; k < part * 64 + 64; ++k)
        s = fmaf(sp[k], P3[k * 32 + j], s);
    red[tid] = s;
    __syncthreads();
    if (tid < 128) red[tid] += red[tid + 128];
    __syncthreads();
    if (tid < 64) red[tid] += red[tid + 64];
    __syncthreads();
    if (tid < 32) out[b * 32 + tid] = red[tid] + red[tid + 32] + pb3[tid];
}

extern "C" void kernel_launch(void* const* d_in, const int* in_sizes, int n_in,
                              void* d_out, int out_size, void* d_ws, size_t ws_size,
                              hipStream_t stream) {
    const float* words = (const float*)d_in[0];
    const int* seg_ids = (const int*)d_in[1];
    const float* W1 = (const float*)d_in[2];
    const float* b1 = (const float*)d_in[3];
    const float* W2 = (const float*)d_in[4];
    const float* b2 = (const float*)d_in[5];
    const float* W3 = (const float*)d_in[6];
    const float* b3 = (const float*)d_in[7];
    const float* P1 = (const float*)d_in[8];
    const float* pb1 = (const float*)d_in[9];
    const float* P2 = (const float*)d_in[10];
    const float* pb2 = (const float*)d_in[11];
    const float* P3 = (const float*)d_in[12];
    const float* pb3 = (const float*)d_in[13];
    float* out = (float*)d_out;

    char* ws = (char*)d_ws;
    _Float16* F1 = (_Float16*)(ws);             // 262144 B
    _Float16* F2 = (_Float16*)(ws + 262144);    // 524288 B
    _Float16* F3 = (_Float16*)(ws + 786432);    // 262144 B
    float* enc = (float*)(ws + 1048576);        // 131072 B

    (void)hipMemsetAsync(enc, 0, 128 * 256 * 4, stream);
    wt_kernel<<<256, 256, 0, stream>>>(W1, W2, W3, F1, F2, F3);
    encoder_kernel<<<1024, 1024, 0, stream>>>(words, seg_ids, F1, F2, F3,
                                              b1, b2, b3, enc);
    pred_kernel<<<128, 256, 0, stream>>>(enc, P1, pb1, P2, pb2, P3, pb3, out);
}

// Round 23
// 212.285 us; speedup vs baseline: 1.0606x; 1.0606x over previous
//
#include <hip/hip_runtime.h>
#include <hip/hip_bf16.h>
#include <hip/hip_fp16.h>

// DeepSetPred FINAL = R21 (measured best: 212.4us total, encoder ~183us).
// R22 (128-tok/16-wave twins) regressed to 225us -> config matrix exhausted;
// reverting to the optimum. Structure:
//  - fused encoder: words->h1->h2->encT->segsum in one kernel, in-place in a
//    64KB swizzled LDS act buffer (64 tokens x 1024B rows, chunk^(t&15) XOR)
//  - weights pre-packed in MFMA A-fragment order (wt_kernel) -> per-wave 1KB
//    contiguous L2 loads, depth-2 ring; NO LDS staging for W, NO intra-layer
//    barriers (free-running waves; latency hidden by 2 anti-phase blocks/CU)
//  - B-frags: single ds_read_b128, 0 measured bank conflicts
//  - 32x32x16 f16 MFMA, MT=2/NT=2, acc 64 AGPR + 64 arch VGPR (reg-file full)
//  - tanh via pre-scaled exp2 + rcp; f16 pack via v_cvt_pkrtz; bias in acc-init
//  - sorted-run segment sum fused into the epilogue (2 atomics/thread)
// Register-budget-pinned plateau: no pipe >33%; deeper rings/other tiles all
// measured worse (R5,R7,R12-R14,R16,R17,R22).

typedef _Float16 half8v __attribute__((ext_vector_type(8)));
typedef _Float16 half4v __attribute__((ext_vector_type(4)));
typedef __fp16 fp16x2 __attribute__((ext_vector_type(2)));
typedef float f32x4 __attribute__((ext_vector_type(4)));
typedef float f32x16 __attribute__((ext_vector_type(16)));

#define TANH_SCALE 2.8853900817779268f  // 2*log2(e)
#define E_STRF 65                       // encT row stride (floats)

__device__ __forceinline__ unsigned pkrtz(float a, float b) {
    fp16x2 p = __builtin_amdgcn_cvt_pkrtz(a, b);
    return __builtin_bit_cast(unsigned, p);
}

// ---------------- weight fragmentizer ----------------
// Frag = [32 f][16 k] in MFMA A order: lane l holds f=ft*32+(l&31),
// k=ks*16+(l>>5)*8+j. Layer layout: frag index = ks*NFT + ft, 1KB each.
__global__ __launch_bounds__(256) void wt_kernel(
    const float* __restrict__ W1, const float* __restrict__ W2,
    const float* __restrict__ W3,
    _Float16* __restrict__ F1, _Float16* __restrict__ F2,
    _Float16* __restrict__ F3) {
    int u = blockIdx.x * 256 + threadIdx.x;       // 65536 lane-units
    const float* W; _Float16* F; int FW, NFT, u0; float scale;
    if (u < 16384)      { W = W1; F = F1; FW = 512; NFT = 16; u0 = u;         scale = TANH_SCALE; }
    else if (u < 49152) { W = W2; F = F2; FW = 512; NFT = 16; u0 = u - 16384; scale = TANH_SCALE; }
    else                { W = W3; F = F3; FW = 256; NFT = 8;  u0 = u - 49152; scale = 1.0f; }
    int lane = u0 & 63, frag = u0 >> 6;
    int ft = frag % NFT, ks = frag / NFT;
    int f = ft * 32 + (lane & 31);
    int k0 = ks * 16 + (lane >> 5) * 8;
    half8v v;
    #pragma unroll
    for (int j = 0; j < 8; ++j)
        v[j] = (_Float16)(W[(size_t)(k0 + j) * FW + f] * scale);
    *(half8v*)((char*)F + (size_t)u0 * 16) = v;
}

// ---------------- encoder pass: D[MT*32 f][64 t] ----------------
// A: global frag-ordered, depth-2 ring (3 buffers). B: LDS b128 swizzled rows,
// depth-1 ring. Act row t: 1024B, 16B chunk c stored at (c<<4)^((t&15)<<4).
template<int K, int MT, int NFT>
__device__ __forceinline__ void mlp_pass32(const char* __restrict__ F, int wave,
                                           const char* lds_act,
                                           const float* sbias_layer, int lane,
                                           f32x16 acc[MT][2]) {
    const int r2 = lane & 31;
    const int hi = lane >> 5;
    const int fbase = wave * (MT * 32);
    #pragma unroll
    for (int mt = 0; mt < MT; ++mt)
        #pragma unroll
        for (int q = 0; q < 4; ++q) {
            f32x4 bv = *(const f32x4*)(sbias_layer + fbase + mt * 32 + hi * 4 + q * 8);
            #pragma unroll
            for (int j = 0; j < 4; ++j) {
                acc[mt][0][q * 4 + j] = bv[j];
                acc[mt][1][q * 4 + j] = bv[j];
            }
        }
    const char* fb = F + ((size_t)wave * MT) * 1024 + lane * 16;
    const int xm = (r2 & 15) << 4;
    const char* bb = lds_act + (size_t)r2 * 1024;

    constexpr int NS = K / 16;
    half8v A[3][MT], B[2][2];
    #pragma unroll
    for (int mt = 0; mt < MT; ++mt) {
        A[0][mt] = *(const half8v*)(fb + mt * 1024);
        A[1][mt] = *(const half8v*)(fb + (NFT + mt) * 1024);
    }
    #pragma unroll
    for (int nt = 0; nt < 2; ++nt)
        B[0][nt] = *(const half8v*)(bb + nt * 32768 + ((hi * 16) ^ xm));

    #pragma unroll
    for (int s = 0; s < NS; ++s) {
        if (s + 2 < NS) {
            #pragma unroll
            for (int mt = 0; mt < MT; ++mt)
                A[(s + 2) % 3][mt] =
                    *(const half8v*)(fb + ((size_t)(s + 2) * NFT + mt) * 1024);
        }
        if (s + 1 < NS) {
            int off = ((((s + 1) * 32) | (hi * 16)) ^ xm);
            #pragma unroll
            for (int nt = 0; nt < 2; ++nt)
                B[(s + 1) & 1][nt] = *(const half8v*)(bb + nt * 32768 + off);
        }
        __builtin_amdgcn_s_setprio(1);
        #pragma unroll
        for (int nt = 0; nt < 2; ++nt)
            #pragma unroll
            for (int mt = 0; mt < MT; ++mt)
                acc[mt][nt] = __builtin_amdgcn_mfma_f32_32x32x16_f16(
                    A[s % 3][mt], B[s & 1][nt], acc[mt][nt], 0, 0, 0);
        __builtin_amdgcn_s_setprio(0);
    }
}

// acc -> tanh -> fp16 LDS via cvt_pkrtz, swizzled [t][chunk ^ (t&15)]
template<int MT>
__device__ __forceinline__ void store_h32(char* lds_out, const f32x16 acc[MT][2],
                                          int fbase, int lane) {
    const int t_lo = lane & 31;
    const int hi = lane >> 5;
    #pragma unroll
    for (int mt = 0; mt < MT; ++mt)
        #pragma unroll
        for (int nt = 0; nt < 2; ++nt) {
            int t = nt * 32 + t_lo;
            int xm = (t & 15) << 4;
            #pragma unroll
            for (int q = 0; q < 4; ++q) {
                int chunk = (fbase >> 3) + mt * 4 + q;
                float th[4];
                #pragma unroll
                for (int j = 0; j < 4; ++j) {
                    float e = __builtin_amdgcn_exp2f(acc[mt][nt][q * 4 + j]);
                    float rr = __builtin_amdgcn_rcpf(e + 1.0f);
                    th[j] = fmaf(-2.0f, rr, 1.0f);
                }
                uint2 u = { pkrtz(th[0], th[1]), pkrtz(th[2], th[3]) };
                *(uint2*)(lds_out + t * 1024 + ((chunk << 4) ^ xm) + hi * 8) = u;
            }
        }
}

__global__ __launch_bounds__(512, 4) void encoder_kernel(
    const float* __restrict__ words, const int* __restrict__ seg_ids,
    const _Float16* __restrict__ F1, const _Float16* __restrict__ F2,
    const _Float16* __restrict__ F3,
    const float* __restrict__ b1, const float* __restrict__ b2,
    const float* __restrict__ b3, float* __restrict__ enc) {
    __shared__ __align__(16) char buf[66560];   // act 64x1024 swz / encT 256x65x4
    __shared__ __align__(16) float sbias[1280];
    __shared__ int sseg[64];

    const int tid = threadIdx.x;
    const int lane = tid & 63;
    const int wave = tid >> 6;
    const int tok0 = blockIdx.x * 64;

    sbias[tid] = b1[tid] * TANH_SCALE;
    sbias[512 + tid] = b2[tid] * TANH_SCALE;
    if (tid < 256) sbias[1024 + tid] = b3[tid];
    if (tid < 64) sseg[tid] = seg_ids[tok0 + tid];

    // stage words tile -> fp16 LDS (cvt_pkrtz), swizzled rows
    const float* wsrc = words + (size_t)tok0 * 256;
    #pragma unroll
    for (int it = 0; it < 8; ++it) {
        int i = it * 512 + tid;            // float4 index, 4096 total
        float4 v = ((const float4*)wsrc)[i];
        int t = i >> 6;
        int col = i & 63;                  // 8B slot within 512B content
        uint2 u = { pkrtz(v.x, v.y), pkrtz(v.z, v.w) };
        int off = t * 1024 + (((col >> 1) << 4) ^ ((t & 15) << 4)) + (col & 1) * 8;
        *(uint2*)(buf + off) = u;
    }
    __syncthreads();

    // layer 1: words[64][256] -> h1[64][512] (in place)
    {
        f32x16 acc[2][2];
        mlp_pass32<256, 2, 16>((const char*)F1, wave, buf, sbias, lane, acc);
        __syncthreads();
        store_h32<2>(buf, acc, wave * 64, lane);
    }
    __syncthreads();

    // layer 2: h1 -> h2 (in place)
    {
        f32x16 acc[2][2];
        mlp_pass32<512, 2, 16>((const char*)F2, wave, buf, sbias + 512, lane, acc);
        __syncthreads();
        store_h32<2>(buf, acc, wave * 64, lane);
    }
    __syncthreads();

    // layer 3: h2 -> encT [256][65] f32 (in place; bias folded, no tanh)
    {
        f32x16 acc[1][2];
        mlp_pass32<512, 1, 8>((const char*)F3, wave, buf, sbias + 1024, lane, acc);
        __syncthreads();
        float* encT = (float*)buf;
        const int t_lo = lane & 31;
        const int hi = lane >> 5;
        #pragma unroll
        for (int nt = 0; nt < 2; ++nt) {
            int t = nt * 32 + t_lo;
            #pragma unroll
            for (int q = 0; q < 4; ++q) {
                int f0 = wave * 32 + hi * 4 + q * 8;
                #pragma unroll
                for (int j = 0; j < 4; ++j)
                    encT[(f0 + j) * E_STRF + t] = acc[0][nt][q * 4 + j];
            }
        }
    }
    __syncthreads();

    // segment reduction: sorted seg_ids -> running sum, atomic on boundary
    {
        int f = tid & 255;
        int hh = tid >> 8;
        int t0 = hh * 32;
        const float* encT = (const float*)buf;
        float a = 0.0f;
        int cur = sseg[t0];
        for (int i = 0; i < 32; ++i) {
            int t = t0 + i;
            float v = encT[f * E_STRF + t];
            int s = sseg[t];
            if (s != cur) { atomicAdd(&enc[cur * 256 + f], a); a = 0.0f; cur = s; }
            a += v;
        }
        atomicAdd(&enc[cur * 256 + f], a);
    }
}

// ---------------- predictor (tiny, fp32) ----------------
__global__ __launch_bounds__(256) void pred_kernel(
    const float* __restrict__ enc,
    const float* __restrict__ P1, const float* __restrict__ pb1,
    const float* __restrict__ P2, const float* __restrict__ pb2,
    const float* __restrict__ P3, const float* __restrict__ pb3,
    float* __restrict__ out) {
    __shared__ float se[256];
    __shared__ float sp[512];
    __shared__ float red[256];
    const int tid = threadIdx.x, b = blockIdx.x;
    se[tid] = enc[b * 256 + tid];
    __syncthreads();
    float a0 = pb1[tid], a1 = pb1[tid + 256];
    for (int k = 0; k < 256; ++k) {
        float e = se[k];
        a0 = fmaf(e, P1[k * 512 + tid], a0);
        a1 = fmaf(e, P1[k * 512 + tid + 256], a1);
    }
    sp[tid] = tanhf(a0);
    sp[tid + 256] = tanhf(a1);
    __syncthreads();
    a0 = pb2[tid]; a1 = pb2[tid + 256];
    for (int k = 0; k < 512; ++k) {
        float p = sp[k];
        a0 = fmaf(p, P2[k * 512 + tid], a0);
        a1 = fmaf(p, P2[k * 512 + tid + 256], a1);
    }
    __syncthreads();
    sp[tid] = tanhf(a0);
    sp[tid + 256] = tanhf(a1);
    __syncthreads();
    int j = tid & 31, part = tid >> 5;
    float s = 0.0f;
    for (int k = part * 64; k < part * 64 + 64; ++k)
        s = fmaf(sp[k], P3[k * 32 + j], s);
    red[tid] = s;
    __syncthreads();
    if (tid < 128) red[tid] += red[tid + 128];
    __syncthreads();
    if (tid < 64) red[tid] += red[tid + 64];
    __syncthreads();
    if (tid < 32) out[b * 32 + tid] = red[tid] + red[tid + 32] + pb3[tid];
}

extern "C" void kernel_launch(void* const* d_in, const int* in_sizes, int n_in,
                              void* d_out, int out_size, void* d_ws, size_t ws_size,
                              hipStream_t stream) {
    const float* words = (const float*)d_in[0];
    const int* seg_ids = (const int*)d_in[1];
    const float* W1 = (const float*)d_in[2];
    const float* b1 = (const float*)d_in[3];
    const float* W2 = (const float*)d_in[4];
    const float* b2 = (const float*)d_in[5];
    const float* W3 = (const float*)d_in[6];
    const float* b3 = (const float*)d_in[7];
    const float* P1 = (const float*)d_in[8];
    const float* pb1 = (const float*)d_in[9];
    const float* P2 = (const float*)d_in[10];
    const float* pb2 = (const float*)d_in[11];
    const float* P3 = (const float*)d_in[12];
    const float* pb3 = (const float*)d_in[13];
    float* out = (float*)d_out;

    char* ws = (char*)d_ws;
    _Float16* F1 = (_Float16*)(ws);             // 262144 B
    _Float16* F2 = (_Float16*)(ws + 262144);    // 524288 B
    _Float16* F3 = (_Float16*)(ws + 786432);    // 262144 B
    float* enc = (float*)(ws + 1048576);        // 131072 B

    (void)hipMemsetAsync(enc, 0, 128 * 256 * 4, stream);
    wt_kernel<<<256, 256, 0, stream>>>(W1, W2, W3, F1, F2, F3);
    encoder_kernel<<<2048, 512, 0, stream>>>(words, seg_ids, F1, F2, F3,
                                             b1, b2, b3, enc);
    pred_kernel<<<128, 256, 0, stream>>>(enc, P1, pb1, P2, pb2, P3, pb3, out);
}